// Round 9
// baseline (1597.244 us; speedup 1.0000x reference)
//
#include <hip/hip_runtime.h>
#include <hip/hip_bf16.h>

// GRU-D fused scan, MFMA broadcast-B edition.
// R5/R7/R8 showed the VALU broadcast-dot structure plateaus at ~1400-1600 us
// (820 v_dot2 floor + ~600 delivery ops, x2 allocator/issue inflation).
// This round moves the matvecs to the matrix pipe:
//   mfma_f32_16x16x32_f16 with B's 16 columns all = h  ->  D columns replicate,
//   so each lane holds its rows' complete gate pre-activations in D regs.
// Wave w (8 waves, 512 thr) owns hidden-unit tile w (16 units), BOTH layers:
//   A-frags (weights, f16) resident ~160 regs (AGPRs fine: MFMA reads AGPR),
//   biases pre-packed as MFMA C-init (f32x4, zero per-step VALU),
//   h_old in registers (wave exclusively owns its units).
// Per step/wave: 42 MFMA + 10 LDS ops (B-frags: 4-addr broadcast ds_read_b128
// from double-buffered LDS h-state) + ~150 VALU (sigm/tanh/update).
// ONE barrier/step (double-buffered state). K=34 input: chunk0 = features
// 0..31; (mask,dt) handled as a sparse K-chunk (quad0-masked B, 3 extra MFMA).
// Layouts (m89/m120-verified): A[m=lane&15][k=(lane>>4)*8+j];
// D: col=lane&15, row=(lane>>4)*4+reg; B assumed k=(lane>>4)*8+j, n=lane&15.

#define BB 256
#define SS 1024
#define DD 32
#define HH 128
#define NT 512

typedef _Float16 f16;
typedef __attribute__((ext_vector_type(2))) _Float16 h2;
typedef __attribute__((ext_vector_type(8))) _Float16 h8;   // MFMA A/B frag
typedef __attribute__((ext_vector_type(4))) float fx4;     // MFMA C/D frag

__device__ inline fx4 mfma(h8 a, h8 b, fx4 c) {
    return __builtin_amdgcn_mfma_f32_16x16x32_f16(a, b, c, 0, 0, 0);
}
__device__ inline h2 as_h2(int x) { union { int i; h2 h; } u; u.i = x; return u.h; }
__device__ inline int h2_int(h2 h) { union { h2 h; int i; } u; u.h = h; return u.i; }

__device__ inline float frcp(float x) { return __builtin_amdgcn_rcpf(x); }
__device__ inline float fast_sigm(float x) { return frcp(1.0f + __expf(-x)); }
__device__ inline float fast_tanh(float x) {
    x = fminf(15.0f, fmaxf(-15.0f, x));
    float e = __expf(-2.0f * x);
    return (1.0f - e) * frcp(1.0f + e);
}

struct ImpState { float xprev, tprev; bool hasprev; };

// Wave 0 only (all 64 lanes active; lane l<32 owns feature l).
__device__ inline void impute_store(int i, float xv, int lane, ImpState& st,
                                    f16* hxd, int* scld, const float* tb) {
    bool nanp = (lane < 32) && (xv != xv);
    unsigned long long bal = __ballot(nanp);
    bool mask = bal != 0ull;
    if (lane < 32) {
        float imp = mask ? st.xprev : xv;
        hxd[lane] = (f16)imp;
        if (!mask) st.xprev = xv;
    }
    float tcur = tb[i];
    float tdel = (i == 0) ? 0.0f : (tcur - tb[i - 1]);
    float texp = st.hasprev ? (tcur - st.tprev) : tdel;
    if (lane == 0) {
        h2 s; s.x = (f16)(mask ? 1.0f : 0.0f); s.y = (f16)texp;
        *scld = h2_int(s);
    }
    if (!mask) { st.hasprev = true; st.tprev = tcur; }
}

__global__ __launch_bounds__(NT, 2) void gru_fused(
    const float* __restrict__ t_in, const float* __restrict__ x_in,
    const float* __restrict__ Wih0, const float* __restrict__ Whh0,
    const float* __restrict__ bih0, const float* __restrict__ bhh0,
    const float* __restrict__ Wih1, const float* __restrict__ Whh1,
    const float* __restrict__ bih1, const float* __restrict__ bhh1,
    float* __restrict__ out)
{
    __shared__ float tb[SS];                       // timestamps (4 KB)
    __shared__ alignas(16) f16 h0s[2][HH];         // h0 state, double-buffered
    __shared__ alignas(16) f16 h1s[2][HH];         // h1 state
    __shared__ alignas(16) f16 hxs[2][32];         // imputed features
    __shared__ int scl[2];                         // packed (mask, texp) h2

    const int tid = threadIdx.x;
    const int lane = tid & 63;
    const int w = tid >> 6;        // wave id = unit-tile (16 units: 16w..16w+15)
    const int q = lane >> 4;       // quad (K-group / D-row-group)
    const int m = lane & 15;       // A row within tile / D col
    const int b = blockIdx.x;

    // ---- A-fragments (weights f32 -> f16), rows = gate g, units 16w+m ----
    // frag element j <-> k = 32c + 8q + j
    h8 whh0f[3][4], wih1f[3][4], whh1f[3][4], wih0c0[3];
    h2 wih0c1[3];                  // (W[row,32], W[row,33])
    #pragma unroll
    for (int g = 0; g < 3; g++) {
        const int row = 128 * g + 16 * w + m;
        const float* pa = Whh0 + (size_t)row * HH;
        const float* pb = Wih1 + (size_t)row * HH;
        const float* pc = Whh1 + (size_t)row * HH;
        const float* pd = Wih0 + (size_t)row * 34;
        #pragma unroll
        for (int c = 0; c < 4; c++) {
            h8 va, vb, vc;
            #pragma unroll
            for (int j = 0; j < 8; j++) {
                int k = 32 * c + 8 * q + j;
                va[j] = (f16)pa[k]; vb[j] = (f16)pb[k]; vc[j] = (f16)pc[k];
            }
            whh0f[g][c] = va; wih1f[g][c] = vb; whh1f[g][c] = vc;
        }
        h8 vd;
        #pragma unroll
        for (int j = 0; j < 8; j++) vd[j] = (f16)pd[8 * q + j];  // k=8q+j<32
        wih0c0[g] = vd;
        h2 t; t.x = (f16)pd[32]; t.y = (f16)pd[33]; wih0c1[g] = t;
    }

    // ---- biases as MFMA C-init (D-layout: element e <-> row 4q+e) ----
    fx4 bR0, bZ0, bNi0, bNh0, bR1, bZ1, bNi1, bNh1;
    #pragma unroll
    for (int e = 0; e < 4; e++) {
        int r4 = 16 * w + 4 * q + e;
        bR0[e]  = bih0[r4] + bhh0[r4];
        bZ0[e]  = bih0[128 + r4] + bhh0[128 + r4];
        bNi0[e] = bih0[256 + r4];
        bNh0[e] = bhh0[256 + r4];
        bR1[e]  = bih1[r4] + bhh1[r4];
        bZ1[e]  = bih1[128 + r4] + bhh1[128 + r4];
        bNi1[e] = bih1[256 + r4];
        bNh1[e] = bhh1[256 + r4];
    }

    // ---- prologue: tb, zero both state slots, impute step 0 ----
    for (int i2 = tid; i2 < SS; i2 += NT) tb[i2] = t_in[i2];
    if (tid < 128)      ((int*)h0s)[tid] = 0;          // both slots (512 B)
    else if (tid < 256) ((int*)h1s)[tid - 128] = 0;

    const float* xrow = x_in + (size_t)b * SS * DD + lane;  // deref lanes<32, wave0
    ImpState st; st.xprev = 0.0f; st.tprev = 0.0f; st.hasprev = false;
    fx4 hn0 = {0.f, 0.f, 0.f, 0.f}, hn1 = {0.f, 0.f, 0.f, 0.f};

    __syncthreads();
    if (w == 0) {
        float xv0 = (lane < 32) ? xrow[0] : 0.0f;
        impute_store(0, xv0, lane, st, hxs[0], &scl[0], tb);
    }
    __syncthreads();

    for (int i = 0; i <= SS; ++i) {
        const int p = i & 1, np = p ^ 1;
        const bool doL0 = (i < SS), doL1 = (i > 0), doImp = (i + 1 < SS);

        float xnext = 0.0f;
        if (w == 0 && lane < 32 && doImp) xnext = xrow[(size_t)(i + 1) * DD];

        // B-frags from h0 state (used by both L0.gh and L1.gx)
        const f16* h0p = h0s[p];
        h8 b0[4];
        #pragma unroll
        for (int c = 0; c < 4; c++) b0[c] = *(const h8*)(h0p + 32 * c + 8 * q);

        // ---- layer 0: step i ----
        if (doL0) {
            h8 bx0 = *(const h8*)(hxs[p] + 8 * q);
            h2 scv = as_h2(scl[p]);
            h8 bx1;
            #pragma unroll
            for (int j = 0; j < 8; j++) bx1[j] = (f16)0.0f;
            bx1[0] = (q == 0) ? scv.x : (f16)0.0f;   // k=32: mask
            bx1[1] = (q == 0) ? scv.y : (f16)0.0f;   // k=33: texp
            fx4 r = bR0, z = bZ0, ni = bNi0, nh = bNh0;
            r  = mfma(wih0c0[0], bx0, r);
            z  = mfma(wih0c0[1], bx0, z);
            ni = mfma(wih0c0[2], bx0, ni);
            #pragma unroll
            for (int g = 0; g < 3; g++) {           // sparse (mask,dt) chunk
                h8 a1;
                #pragma unroll
                for (int j = 0; j < 8; j++) a1[j] = (f16)0.0f;
                a1[0] = wih0c1[g].x; a1[1] = wih0c1[g].y;
                if (g == 0) r = mfma(a1, bx1, r);
                else if (g == 1) z = mfma(a1, bx1, z);
                else ni = mfma(a1, bx1, ni);
            }
            #pragma unroll
            for (int c = 0; c < 4; c++) {
                r  = mfma(whh0f[0][c], b0[c], r);
                z  = mfma(whh0f[1][c], b0[c], z);
                nh = mfma(whh0f[2][c], b0[c], nh);
            }
            #pragma unroll
            for (int e = 0; e < 4; e++) {
                float rr = fast_sigm(r[e]);
                float zz = fast_sigm(z[e]);
                float nn = fast_tanh(ni[e] + rr * nh[e]);
                hn0[e] = (1.0f - zz) * nn + zz * hn0[e];
            }
            if (m == 0) {   // publish 4 units (rows 4q..4q+3) to next slot
                h2 lo; lo.x = (f16)hn0[0]; lo.y = (f16)hn0[1];
                h2 hi; hi.x = (f16)hn0[2]; hi.y = (f16)hn0[3];
                h2* dst = (h2*)(h0s[np] + 16 * w + 4 * q);
                dst[0] = lo; dst[1] = hi;
            }
        }

        // ---- layer 1: step i-1 ----
        if (doL1) {
            fx4 r1 = bR1, z1 = bZ1, ni1 = bNi1, nh1 = bNh1;
            #pragma unroll
            for (int c = 0; c < 4; c++) {
                r1  = mfma(wih1f[0][c], b0[c], r1);
                z1  = mfma(wih1f[1][c], b0[c], z1);
                ni1 = mfma(wih1f[2][c], b0[c], ni1);
            }
            const f16* h1p = h1s[p];
            h8 b1[4];
            #pragma unroll
            for (int c = 0; c < 4; c++) b1[c] = *(const h8*)(h1p + 32 * c + 8 * q);
            #pragma unroll
            for (int c = 0; c < 4; c++) {
                r1  = mfma(whh1f[0][c], b1[c], r1);
                z1  = mfma(whh1f[1][c], b1[c], z1);
                nh1 = mfma(whh1f[2][c], b1[c], nh1);
            }
            #pragma unroll
            for (int e = 0; e < 4; e++) {
                float rr = fast_sigm(r1[e]);
                float zz = fast_sigm(z1[e]);
                float nn = fast_tanh(ni1[e] + rr * nh1[e]);
                hn1[e] = (1.0f - zz) * nn + zz * hn1[e];
            }
            if (m == 0) {
                h2 lo; lo.x = (f16)hn1[0]; lo.y = (f16)hn1[1];
                h2 hi; hi.x = (f16)hn1[2]; hi.y = (f16)hn1[3];
                h2* dst = (h2*)(h1s[np] + 16 * w + 4 * q);
                dst[0] = lo; dst[1] = hi;
            }
        }

        // ---- imputation for step i+1 (wave 0) ----
        if (w == 0 && doImp)
            impute_store(i + 1, xnext, lane, st, hxs[np], &scl[np], tb);

        __syncthreads();   // single barrier: publishes to slot np visible;
                           // slot p reads all happened pre-barrier (safe)
    }

    if (m == 0) {   // lane (q, m=0) holds final h1 for units 16w+4q..+3
        *(fx4*)(out + (size_t)b * HH + 16 * w + 4 * q) = hn1;
    }
}

extern "C" void kernel_launch(void* const* d_in, const int* in_sizes, int n_in,
                              void* d_out, int out_size, void* d_ws, size_t ws_size,
                              hipStream_t stream) {
    gru_fused<<<dim3(BB), dim3(NT), 0, stream>>>(
        (const float*)d_in[0], (const float*)d_in[1],
        (const float*)d_in[2], (const float*)d_in[3],
        (const float*)d_in[4], (const float*)d_in[5],
        (const float*)d_in[6], (const float*)d_in[7],
        (const float*)d_in[8], (const float*)d_in[9],
        (float*)d_out);
}